// Round 4
// baseline (115.043 us; speedup 1.0000x reference)
//
#include <hip/hip_runtime.h>
#include <math.h>

#define NN 8192
#define EPSF 1e-6f
#define R 16                // rows per block
#define GX (NN / R)         // 512 blocks

// ws layout:
//   pack[NN]  : float4 {T[j], exp(Pr[j]), E[j]*exp(Ps[j]), 0}   (131072 B)
//   sumR[NN]  : float  (zeroed by prep; atomicAdd targets)       (32768 B)
//   sumS[NN]  : float                                            (32768 B)
//   ticket    : unsigned int                                     (4 B)

__global__ __launch_bounds__(256) void ds_prep(
    const float* __restrict__ Pr, const float* __restrict__ Ps,
    const float* __restrict__ T,  const int* __restrict__ E,
    float4* __restrict__ pack, float* __restrict__ sumR, float* __restrict__ sumS,
    unsigned int* __restrict__ ticket) {
  int i = blockIdx.x * 256 + threadIdx.x;
  float t  = T[i];
  float er = __expf(Pr[i]);
  float es = E[i] ? __expf(Ps[i]) : 0.0f;
  pack[i] = make_float4(t, er, es, 0.0f);
  sumR[i] = 0.0f;
  sumS[i] = 0.0f;
  if (i == 0) *ticket = 0u;
}

// Fused main + finalize. Block b owns rows [b*R, b*R+R), streams ALL j with
// lane-coalesced float4 loads (VMEM pipe). Complete per-row sums -> one
// device-scope atomicAdd per row. Last block (ticket) computes the losses.
__global__ __launch_bounds__(256) void ds_main(
    const float* __restrict__ T, const float4* __restrict__ pack,
    const float* __restrict__ Pr, const float* __restrict__ Ps,
    const int* __restrict__ E,
    float* __restrict__ sumR, float* __restrict__ sumS,
    unsigned int* __restrict__ ticket, float* __restrict__ out) {
  const int tid  = threadIdx.x;
  const int row0 = blockIdx.x * R;

  float Ti[R];
#pragma unroll
  for (int r = 0; r < R; ++r) Ti[r] = T[row0 + r];   // block-uniform -> SGPR

  float sr[R], ss[R];
#pragma unroll
  for (int r = 0; r < R; ++r) { sr[r] = 0.0f; ss[r] = 0.0f; }

  for (int k = 0; k < NN; k += 256 * 4) {
    float4 p0 = pack[k + tid];
    float4 p1 = pack[k + 256 + tid];
    float4 p2 = pack[k + 512 + tid];
    float4 p3 = pack[k + 768 + tid];
#pragma unroll
    for (int r = 0; r < R; ++r) {
      bool g0 = p0.x > Ti[r];
      sr[r] += g0 ? p0.y : 0.0f;  ss[r] += g0 ? 0.0f : p0.z;
      bool g1 = p1.x > Ti[r];
      sr[r] += g1 ? p1.y : 0.0f;  ss[r] += g1 ? 0.0f : p1.z;
      bool g2 = p2.x > Ti[r];
      sr[r] += g2 ? p2.y : 0.0f;  ss[r] += g2 ? 0.0f : p2.z;
      bool g3 = p3.x > Ti[r];
      sr[r] += g3 ? p3.y : 0.0f;  ss[r] += g3 ? 0.0f : p3.z;
    }
  }

  // wave shuffle reduction, then cross-wave via LDS
#pragma unroll
  for (int r = 0; r < R; ++r) {
    for (int off = 32; off > 0; off >>= 1) {
      sr[r] += __shfl_down(sr[r], off);
      ss[r] += __shfl_down(ss[r], off);
    }
  }
  __shared__ float sh[4][2 * R];
  const int wid = tid >> 6, lane = tid & 63;
  if (lane == 0) {
#pragma unroll
    for (int r = 0; r < R; ++r) { sh[wid][r] = sr[r]; sh[wid][R + r] = ss[r]; }
  }
  __syncthreads();
  if (tid < 2 * R) {
    float v = sh[0][tid] + sh[1][tid] + sh[2][tid] + sh[3][tid];
    if (tid < R) {
      atomicAdd(&sumR[row0 + tid], v);        // device-coherent write
    } else {
      int r = tid - R;
      // complement (T[j] <= T[i]) included the diagonal; remove exactly.
      atomicAdd(&sumS[row0 + r], v - pack[row0 + r].z);
    }
  }
  __threadfence();
  __syncthreads();                            // drains vmcnt before ticket

  __shared__ unsigned int my_ticket;
  if (tid == 0) my_ticket = atomicAdd(ticket, 1u);
  __syncthreads();
  if (my_ticket != (unsigned int)(GX - 1)) return;

  // --- last block: finalize the two scalar losses ---
  float nr = 0.0f, dr = 0.0f, ns = 0.0f, nds = 0.0f;
  for (int i = tid; i < NN; i += 256) {
    float srv = atomicAdd(&sumR[i], 0.0f);    // coherent read (cross-XCD safe)
    float ssv = atomicAdd(&sumS[i], 0.0f);
    float er = (E[i] != 0 && srv > 0.0f) ? 1.0f : 0.0f;
    float es = (ssv > 0.0f) ? 1.0f : 0.0f;
    nr  += er * (Pr[i] - logf(srv + EPSF));
    dr  += er;
    ns  += es * (Ps[i] - logf(ssv + EPSF));
    nds += es;
  }
  for (int off = 32; off > 0; off >>= 1) {
    nr  += __shfl_down(nr,  off);
    dr  += __shfl_down(dr,  off);
    ns  += __shfl_down(ns,  off);
    nds += __shfl_down(nds, off);
  }
  __shared__ float fin[4][4];
  if (lane == 0) {
    fin[0][wid] = nr; fin[1][wid] = dr; fin[2][wid] = ns; fin[3][wid] = nds;
  }
  __syncthreads();
  if (tid == 0) {
    float NR = fin[0][0] + fin[0][1] + fin[0][2] + fin[0][3];
    float DR = fin[1][0] + fin[1][1] + fin[1][2] + fin[1][3];
    float NS = fin[2][0] + fin[2][1] + fin[2][2] + fin[2][3];
    float DS = fin[3][0] + fin[3][1] + fin[3][2] + fin[3][3];
    out[0] = -NR / DR;
    out[1] = -NS / DS;
  }
}

extern "C" void kernel_launch(void* const* d_in, const int* in_sizes, int n_in,
                              void* d_out, int out_size, void* d_ws, size_t ws_size,
                              hipStream_t stream) {
  const float* Pr = (const float*)d_in[0];
  const float* Ps = (const float*)d_in[1];
  const float* T  = (const float*)d_in[2];
  const int*   E  = (const int*)d_in[3];
  float* out = (float*)d_out;

  char* ws = (char*)d_ws;
  float4* pack = (float4*)ws;
  float*  sumR = (float*)(ws + (size_t)NN * sizeof(float4));
  float*  sumS = sumR + NN;
  unsigned int* ticket = (unsigned int*)(sumS + NN);

  ds_prep<<<NN / 256, 256, 0, stream>>>(Pr, Ps, T, E, pack, sumR, sumS, ticket);
  ds_main<<<GX, 256, 0, stream>>>(T, pack, Pr, Ps, E, sumR, sumS, ticket, out);
}

// Round 5
// 73.703 us; speedup vs baseline: 1.5609x; 1.5609x over previous
//
#include <hip/hip_runtime.h>
#include <math.h>

#define NN 8192
#define EPSF 1e-6f
#define R 8                 // rows per block
#define GX (NN / R)         // 1024 blocks

// ws layout: part[GX] float4 {nr, dr, ns, nds} per-block partials (16 KB).
// Every slot is written every call -> no zero-init needed despite 0xAA poison.
// Cross-kernel visibility via kernel boundary (R3-proven), no fences/atomics.

__global__ __launch_bounds__(256) void ds_main(
    const float* __restrict__ Pr, const float* __restrict__ Ps,
    const float* __restrict__ T,  const int* __restrict__ E,
    float4* __restrict__ part) {
  const int tid  = threadIdx.x;
  const int row0 = blockIdx.x * R;

  float Ti[R];
#pragma unroll
  for (int r = 0; r < R; ++r) Ti[r] = T[row0 + r];   // block-uniform -> s_load

  float sr[R], ss[R];
#pragma unroll
  for (int r = 0; r < R; ++r) { sr[r] = 0.0f; ss[r] = 0.0f; }

  // Stream raw inputs with lane-coalesced dwordx4 loads; prep fused (exp on
  // the fly). 8 chunks of 1024 j; 4 loads in flight per thread.
  for (int k = 0; k < NN; k += 1024) {
    const int j = k + tid * 4;
    float4 t4  = *(const float4*)(T  + j);
    float4 pr4 = *(const float4*)(Pr + j);
    float4 ps4 = *(const float4*)(Ps + j);
    int4   e4  = *(const int4*)(E  + j);
    float er0 = __expf(pr4.x), er1 = __expf(pr4.y),
          er2 = __expf(pr4.z), er3 = __expf(pr4.w);
    float es0 = e4.x ? __expf(ps4.x) : 0.0f;
    float es1 = e4.y ? __expf(ps4.y) : 0.0f;
    float es2 = e4.z ? __expf(ps4.z) : 0.0f;
    float es3 = e4.w ? __expf(ps4.w) : 0.0f;
#pragma unroll
    for (int r = 0; r < R; ++r) {
      bool g0 = t4.x > Ti[r];  sr[r] += g0 ? er0 : 0.0f;  ss[r] += g0 ? 0.0f : es0;
      bool g1 = t4.y > Ti[r];  sr[r] += g1 ? er1 : 0.0f;  ss[r] += g1 ? 0.0f : es1;
      bool g2 = t4.z > Ti[r];  sr[r] += g2 ? er2 : 0.0f;  ss[r] += g2 ? 0.0f : es2;
      bool g3 = t4.w > Ti[r];  sr[r] += g3 ? er3 : 0.0f;  ss[r] += g3 ? 0.0f : es3;
    }
  }

  // wave shuffle reduction, then cross-wave via LDS
#pragma unroll
  for (int r = 0; r < R; ++r) {
    for (int off = 32; off > 0; off >>= 1) {
      sr[r] += __shfl_down(sr[r], off);
      ss[r] += __shfl_down(ss[r], off);
    }
  }
  __shared__ float sh[4][2 * R];
  const int wid = tid >> 6, lane = tid & 63;
  if (lane == 0) {
#pragma unroll
    for (int r = 0; r < R; ++r) { sh[wid][r] = sr[r]; sh[wid][R + r] = ss[r]; }
  }
  __syncthreads();
  __shared__ float fin[2 * R];
  if (tid < 2 * R)
    fin[tid] = sh[0][tid] + sh[1][tid] + sh[2][tid] + sh[3][tid];
  __syncthreads();

  // per-row loss contributions (lanes 0..R-1 of wave 0), reduce to 4 scalars
  float nr = 0.0f, dr = 0.0f, ns = 0.0f, nds = 0.0f;
  if (tid < R) {
    const int   row = row0 + tid;
    const int   e   = E[row];
    const float prv = Pr[row], psv = Ps[row];
    const float es_diag = e ? __expf(psv) : 0.0f;  // identical expr to inner -> exact
    const float srv = fin[tid];
    const float ssv = fin[R + tid] - es_diag;      // complement included diagonal
    const float wr = (e != 0 && srv > 0.0f) ? 1.0f : 0.0f;
    const float wsv = (ssv > 0.0f) ? 1.0f : 0.0f;
    nr  = wr  * (prv - logf(srv + EPSF));
    dr  = wr;
    ns  = wsv * (psv - logf(ssv + EPSF));
    nds = wsv;
  }
  if (tid < 64) {   // wave 0: binary-tree reduce lanes 0..7
#pragma unroll
    for (int off = R / 2; off > 0; off >>= 1) {
      nr  += __shfl_down(nr,  off);
      dr  += __shfl_down(dr,  off);
      ns  += __shfl_down(ns,  off);
      nds += __shfl_down(nds, off);
    }
    if (tid == 0) part[blockIdx.x] = make_float4(nr, dr, ns, nds);
  }
}

__global__ __launch_bounds__(256) void ds_finalize(
    const float4* __restrict__ part, float* __restrict__ out) {
  float nr = 0.0f, dr = 0.0f, ns = 0.0f, nds = 0.0f;
  for (int i = threadIdx.x; i < GX; i += 256) {
    float4 p = part[i];
    nr += p.x; dr += p.y; ns += p.z; nds += p.w;
  }
  for (int off = 32; off > 0; off >>= 1) {
    nr  += __shfl_down(nr,  off);
    dr  += __shfl_down(dr,  off);
    ns  += __shfl_down(ns,  off);
    nds += __shfl_down(nds, off);
  }
  __shared__ float sh[4][4];
  const int wid = threadIdx.x >> 6, lane = threadIdx.x & 63;
  if (lane == 0) {
    sh[0][wid] = nr; sh[1][wid] = dr; sh[2][wid] = ns; sh[3][wid] = nds;
  }
  __syncthreads();
  if (threadIdx.x == 0) {
    float NR = sh[0][0] + sh[0][1] + sh[0][2] + sh[0][3];
    float DR = sh[1][0] + sh[1][1] + sh[1][2] + sh[1][3];
    float NS = sh[2][0] + sh[2][1] + sh[2][2] + sh[2][3];
    float DS = sh[3][0] + sh[3][1] + sh[3][2] + sh[3][3];
    out[0] = -NR / DR;
    out[1] = -NS / DS;
  }
}

extern "C" void kernel_launch(void* const* d_in, const int* in_sizes, int n_in,
                              void* d_out, int out_size, void* d_ws, size_t ws_size,
                              hipStream_t stream) {
  const float* Pr = (const float*)d_in[0];
  const float* Ps = (const float*)d_in[1];
  const float* T  = (const float*)d_in[2];
  const int*   E  = (const int*)d_in[3];
  float* out = (float*)d_out;

  float4* part = (float4*)d_ws;   // GX float4 = 16 KB

  ds_main<<<GX, 256, 0, stream>>>(Pr, Ps, T, E, part);
  ds_finalize<<<1, 256, 0, stream>>>(part, out);
}